// Round 7
// baseline (133.054 us; speedup 1.0000x reference)
//
#include <hip/hip_runtime.h>

#define CROP_S 14
#define NPIX   196                  // 14*14
#define NCH    256
#define CPB    16                   // channels per work-item
#define NGRP   (NCH / CPB)          // 16 items per proposal
#define PROWS  12
#define PCOLS  16
#define PSZ    (PROWS * PCOLS)      // 192 floats per channel
#define ITEMS  8                    // work-items per block

struct Ctx {
    const float* fbase;   // level base + c0*HW + xlo4
    int   M, HW, ylo;
    float wx, wy;
    int   o00;
    float* op;            // out + n*NCH*NPIX + c0*NPIX + tid
};

__global__ __launch_bounds__(256) void roi_crop_kernel(
    const float* __restrict__ f0, const float* __restrict__ f1,
    const float* __restrict__ f2, const float* __restrict__ f3,
    const float* __restrict__ proposals, float* __restrict__ out,
    int n_items)
{
    __shared__ float s_patch[CPB * PSZ];     // 12 KB
    const int tid = threadIdx.x;
    const int b   = blockIdx.x;
    const int strideb = gridDim.x;

    auto make_ctx = [&](float px0, float py0, float px1, float py1,
                        int item, Ctx& ic) {
        const float size = sqrtf((px1 - px0) * (py1 - py0));
        int lvl = 0; float bd = fabsf(size - 8.f), d;
        d = fabsf(size - 16.f); if (d < bd) { bd = d; lvl = 1; }
        d = fabsf(size - 32.f); if (d < bd) { bd = d; lvl = 2; }
        d = fabsf(size - 64.f); if (d < bd) { bd = d; lvl = 3; }
        const float* f = (lvl==0)?f0:(lvl==1)?f1:(lvl==2)?f2:f3;
        const float inv = (lvl==0)?0.5f:(lvl==1)?0.25f:(lvl==2)?0.125f:0.0625f; // exact
        const int M = 256 >> lvl;
        ic.M = M; ic.HW = M * M;
        const float x0s = px0*inv, y0s = py0*inv, x1s = px1*inv, y1s = py1*inv;
        const float bw = (x1s - x0s) * (1.f/CROP_S);
        const float bh = (y1s - y0s) * (1.f/CROP_S);
        ic.ylo = min(max((int)floorf(y0s + 0.5f*bh - 0.5f), 0), M-1);
        int xlo4 = (min(max((int)floorf(x0s + 0.5f*bw - 0.5f), 0), M-1)) & ~3;
        xlo4 = min(xlo4, M - PCOLS);
        const int n  = item >> 4;
        const int c0 = (item & 15) * CPB;
        ic.fbase = f + (size_t)c0 * ic.HW + xlo4;
        // per-pixel bilinear state (valid for tid<NPIX; clamped otherwise)
        const int y = tid / CROP_S;
        const int x = tid - y * CROP_S;
        const float xs = x0s + ((float)x + 0.5f)*bw - 0.5f;
        const float ys = y0s + ((float)y + 0.5f)*bh - 0.5f;
        const float fx = floorf(xs), fy = floorf(ys);
        ic.wx = xs - fx; ic.wy = ys - fy;      // frac BEFORE clip (matches ref)
        const int xi0 = min(max((int)fx, 0), M-1);
        const int yi0 = min(max((int)fy, 0), M-1);
        const int ci0 = min(max(xi0 - xlo4, 0), PCOLS-2);  // xi1==xi0+1 always
        const int ri0 = min(max(yi0 - ic.ylo, 0), PROWS-2);
        ic.o00 = ri0 * PCOLS + ci0;
        ic.op  = out + (size_t)n * (NCH*NPIX) + (size_t)c0 * NPIX + tid;
    };

    auto issue = [&](const Ctx& ic, float4& v0, float4& v1, float4& v2) {
        const float* fb = ic.fbase;
        const int M = ic.M, HW = ic.HW, ylo = ic.ylo;
        {   const int sidx = tid;
            const int c = sidx / 48, rem = sidx - c*48;
            const int gy = min(ylo + (rem>>2), M-1);
            v0 = *reinterpret_cast<const float4*>(fb + (size_t)c*HW + gy*M + (rem&3)*4); }
        {   const int sidx = 256 + tid;
            const int c = sidx / 48, rem = sidx - c*48;
            const int gy = min(ylo + (rem>>2), M-1);
            v1 = *reinterpret_cast<const float4*>(fb + (size_t)c*HW + gy*M + (rem&3)*4); }
        {   const int sidx = 512 + tid;
            const int c = sidx / 48, rem = sidx - c*48;
            const int gy = min(ylo + (rem>>2), M-1);
            v2 = *reinterpret_cast<const float4*>(fb + (size_t)c*HW + gy*M + (rem&3)*4); }
    };

    auto stage_write = [&](const float4& v0, const float4& v1, const float4& v2) {
        *reinterpret_cast<float4*>(&s_patch[(size_t)tid*4])       = v0;
        *reinterpret_cast<float4*>(&s_patch[(size_t)(256+tid)*4]) = v1;
        *reinterpret_cast<float4*>(&s_patch[(size_t)(512+tid)*4]) = v2;
    };

    auto interp = [&](const Ctx& ic) {
        if (tid < NPIX) {
            const float wx = ic.wx, wy = ic.wy;
            float* op = ic.op;
            #pragma unroll
            for (int c = 0; c < CPB; ++c) {
                const float* pp = s_patch + c*PSZ + ic.o00;
                const float v00 = pp[0], v10 = pp[PCOLS];
                const float v01 = pp[1], v11 = pp[PCOLS+1];
                const float r0 = v00 + wx*(v01 - v00);
                const float r1 = v10 + wx*(v11 - v10);
                __builtin_nontemporal_store(r0 + wy*(r1 - r0), op + c*NPIX);
            }
        }
    };

    Ctx    ic[2];
    float4 sv[2][3];
    float  pr[2][4];

    // ---- software pipeline prologue ----
    {   const int n0 = b >> 4;
        pr[0][0] = proposals[n0*7+1]; pr[0][1] = proposals[n0*7+2];
        pr[0][2] = proposals[n0*7+3]; pr[0][3] = proposals[n0*7+4]; }
    make_ctx(pr[0][0],pr[0][1],pr[0][2],pr[0][3], b, ic[0]);
    issue(ic[0], sv[0][0], sv[0][1], sv[0][2]);
    {   const int item1 = b + strideb;
        if (item1 < n_items) {
            const int n1 = item1 >> 4;
            pr[1][0] = proposals[n1*7+1]; pr[1][1] = proposals[n1*7+2];
            pr[1][2] = proposals[n1*7+3]; pr[1][3] = proposals[n1*7+4]; } }

    #pragma unroll
    for (int k = 0; k < ITEMS; ++k) {
        const int cur = k & 1, nxt = cur ^ 1;
        if (b + k*strideb >= n_items) break;           // block-uniform
        stage_write(sv[cur][0], sv[cur][1], sv[cur][2]);  // waits vmcnt on sv[cur]
        __syncthreads();
        if (k < ITEMS-1 && b + (k+1)*strideb < n_items) {
            make_ctx(pr[nxt][0],pr[nxt][1],pr[nxt][2],pr[nxt][3],
                     b + (k+1)*strideb, ic[nxt]);
            issue(ic[nxt], sv[nxt][0], sv[nxt][1], sv[nxt][2]);  // in flight over interp
            if (k < ITEMS-2 && b + (k+2)*strideb < n_items) {
                const int n2 = (b + (k+2)*strideb) >> 4;
                pr[cur][0] = proposals[n2*7+1]; pr[cur][1] = proposals[n2*7+2];
                pr[cur][2] = proposals[n2*7+3]; pr[cur][3] = proposals[n2*7+4];
            }
        }
        interp(ic[cur]);
        __syncthreads();
    }
}

extern "C" void kernel_launch(void* const* d_in, const int* in_sizes, int n_in,
                              void* d_out, int out_size, void* d_ws, size_t ws_size,
                              hipStream_t stream) {
    const float* f0 = (const float*)d_in[0];
    const float* f1 = (const float*)d_in[1];
    const float* f2 = (const float*)d_in[2];
    const float* f3 = (const float*)d_in[3];
    const float* proposals = (const float*)d_in[4];
    float* out = (float*)d_out;

    const int N = in_sizes[4] / 7;           // 1024 proposals
    const int n_items = N * NGRP;            // 16384
    const int grid = (n_items + ITEMS - 1) / ITEMS;   // 2048

    roi_crop_kernel<<<dim3(grid), dim3(256), 0, stream>>>(
        f0, f1, f2, f3, proposals, out, n_items);
}

// Round 9
// 56.565 us; speedup vs baseline: 2.3522x; 2.3522x over previous
//
#include <hip/hip_runtime.h>

#define CROP_S 14
#define NPIX   196                  // 14*14
#define NCH    256
#define CPB    16                   // channels per block
#define NGRP   (NCH / CPB)          // 16 blocks per proposal
#define PROWS  12                   // patch rows (span provably <= 12)
#define PCOLS  16                   // patch cols (span<=11 + <=3 align slack, float4-aligned)
#define PSZ    (PROWS * PCOLS)      // 192 floats per channel
#define STAGE_V4 (CPB * PSZ / 4)    // 768 float4 loads -> 3 per thread
#define OUTF   (CPB * NPIX)         // 3136 floats per item
#define OUTV4  (OUTF / 4)           // 784 float4 per item

typedef float v4f __attribute__((ext_vector_type(4)));

__global__ __launch_bounds__(256) void roi_crop_kernel(
    const float* __restrict__ f0, const float* __restrict__ f1,
    const float* __restrict__ f2, const float* __restrict__ f3,
    const float* __restrict__ proposals, float* __restrict__ out)
{
    __shared__ float s_patch[CPB * PSZ];      // 12 KB: [c][12][16]
    __shared__ float s_out[OUTF];             // 12.25 KB: [c][196]

    const int bid = blockIdx.x;
    const int n   = bid >> 4;          // proposal
    const int cg  = bid & (NGRP - 1);  // channel group
    const int c0  = cg * CPB;
    const int tid = threadIdx.x;

    // ---- per-proposal box / level (uniform across block; L2-hit loads) ----
    const float px0 = proposals[n * 7 + 1];
    const float py0 = proposals[n * 7 + 2];
    const float px1 = proposals[n * 7 + 3];
    const float py1 = proposals[n * 7 + 4];

    const float size = sqrtf((px1 - px0) * (py1 - py0));
    int lvl = 0;
    float bd = fabsf(size - 8.0f);
    {
        float d1 = fabsf(size - 16.0f);
        if (d1 < bd) { bd = d1; lvl = 1; }
        float d2 = fabsf(size - 32.0f);
        if (d2 < bd) { bd = d2; lvl = 2; }
        float d3 = fabsf(size - 64.0f);
        if (d3 < bd) { bd = d3; lvl = 3; }
    }

    const float* f = (lvl == 0) ? f0 : (lvl == 1) ? f1 : (lvl == 2) ? f2 : f3;
    const float stride = (float)(2 << lvl);   // 2,4,8,16 (pow2 -> exact divide)
    const int   M      = 256 >> lvl;          // H == W
    const int   HW     = M * M;

    const float x0s = px0 / stride, y0s = py0 / stride;
    const float x1s = px1 / stride, y1s = py1 / stride;
    const float bw = (x1s - x0s) / (float)CROP_S;
    const float bh = (y1s - y0s) / (float)CROP_S;

    // patch origin: floor of minimal sample coord; x aligned down to float4
    const int ylo  = min(max((int)floorf(y0s + 0.5f * bh - 0.5f), 0), M - 1);
    int xlo4 = min(max((int)floorf(x0s + 0.5f * bw - 0.5f), 0), M - 1) & ~3;
    xlo4 = min(xlo4, M - PCOLS);              // vector loads stay inside tensor

    // ---- stage CPB channels x 12x16 patch via float4 (3 per thread) ----
    {
        const float* fbase = f + (size_t)c0 * HW + xlo4;
        #pragma unroll
        for (int it = 0; it < STAGE_V4 / 256; ++it) {
            const int sidx = it * 256 + tid;         // [0,768)
            const int c    = sidx / (PSZ / 4);       // /48
            const int rem  = sidx - c * (PSZ / 4);
            const int r    = rem >> 2;               // row 0..11
            const int q    = rem & 3;                // col quad
            const int gy   = min(ylo + r, M - 1);    // edge-replicate rows
            const v4f v = *reinterpret_cast<const v4f*>(
                fbase + (size_t)c * HW + gy * M + q * 4);
            *reinterpret_cast<v4f*>(&s_patch[sidx * 4]) = v;
        }
    }
    __syncthreads();

    // ---- interp into LDS output tile (pixel-per-lane, register state) ----
    if (tid < NPIX) {
        const int y = tid / CROP_S;
        const int x = tid - y * CROP_S;
        const float xs = x0s + ((float)x + 0.5f) * bw - 0.5f;
        const float ys = y0s + ((float)y + 0.5f) * bh - 0.5f;
        const float fx = floorf(xs), fy = floorf(ys);
        const float wx = xs - fx;                 // frac BEFORE clip (matches ref)
        const float wy = ys - fy;
        // Upper clamp provably never binds: xi1 == xi0+1, yi1 == yi0+1 always.
        const int xi0 = min(max((int)fx, 0), M - 1);
        const int yi0 = min(max((int)fy, 0), M - 1);
        const int ci0 = min(xi0 - xlo4, PCOLS - 2);
        const int ri0 = min(yi0 - ylo,  PROWS - 2);
        const int o00 = ri0 * PCOLS + ci0;        // corners at +0, +1, +16, +17

        #pragma unroll
        for (int c = 0; c < CPB; ++c) {
            const float* pp = s_patch + c * PSZ + o00;
            const float v00 = pp[0];
            const float v10 = pp[PCOLS];
            const float v01 = pp[1];
            const float v11 = pp[PCOLS + 1];
            const float r0 = v00 + wx * (v01 - v00);
            const float r1 = v10 + wx * (v11 - v10);
            s_out[c * NPIX + tid] = r0 + wy * (r1 - r0);
        }
    }
    __syncthreads();

    // ---- cooperative full-line float4 writeout (all 256 lanes) ----
    v4f* ob = reinterpret_cast<v4f*>(
        out + (size_t)n * (NCH * NPIX) + (size_t)c0 * NPIX);  // 3136B offset, 16B-aligned
    #pragma unroll
    for (int i = 0; i < 4; ++i) {
        const int idx = i * 256 + tid;           // [0,1024) vs OUTV4=784
        if (idx < OUTV4) {
            const v4f v = *reinterpret_cast<const v4f*>(&s_out[idx * 4]);
            __builtin_nontemporal_store(v, ob + idx);
        }
    }
}

extern "C" void kernel_launch(void* const* d_in, const int* in_sizes, int n_in,
                              void* d_out, int out_size, void* d_ws, size_t ws_size,
                              hipStream_t stream) {
    const float* f0 = (const float*)d_in[0];
    const float* f1 = (const float*)d_in[1];
    const float* f2 = (const float*)d_in[2];
    const float* f3 = (const float*)d_in[3];
    const float* proposals = (const float*)d_in[4];
    float* out = (float*)d_out;

    const int N = in_sizes[4] / 7;   // 1024 proposals

    roi_crop_kernel<<<dim3(N * NGRP), dim3(256), 0, stream>>>(f0, f1, f2, f3, proposals, out);
}